// Round 4
// baseline (325.185 us; speedup 1.0000x reference)
//
#include <hip/hip_runtime.h>
#include <cstdint>

#define B8   8
#define DIN  1024
#define NH1  2048
#define NH2  1024
#define NOUT 5120

__device__ __forceinline__ float4 ld4(const float* p) {
  return *reinterpret_cast<const float4*>(p);
}
__device__ __forceinline__ void st4(float* p, float4 v) {
  *reinterpret_cast<float4*>(p) = v;
}

// C_parts[kb][8][N] = A[8, k0:k0+KC] @ W[k0:k0+KC, :]   (partial over K-chunk)
// A source: raw input (NPART==0) or sum of NPART partials + bias (+ReLU).
// The staged (finalized) A chunk is optionally written out (features).
template<int K, int N, int KSPLIT, int NPART, bool RELU_IN, bool WRITE_STAGE>
__global__ __launch_bounds__(256)
void gemm8(const float* __restrict__ Asrc, const float* __restrict__ bias_in,
           const float* __restrict__ W, float* __restrict__ Cparts,
           float* __restrict__ stage_out)
{
  constexpr int KC    = K / KSPLIT;   // k-chunk per block
  constexpr int KC4   = KC / 4;
  constexpr int NCOLB = N / 64;       // 64 output cols per block
  constexpr int KT    = KC / 16;      // k elements per thread

  __shared__ float A_lds[8][KC];      // <= 8 KB
  __shared__ float red[16][8][64];    // 32 KB

  const int tid = threadIdx.x;
  const int kb  = blockIdx.x / NCOLB;
  const int cb  = blockIdx.x % NCOLB;
  const int k0  = kb * KC;

  // ---- stage A chunk into LDS (finalize previous stage: sum partials + bias + relu)
  for (int e = tid; e < 8 * KC4; e += 256) {
    const int b = e / KC4, k4 = e - b * KC4;
    float4 v;
    if constexpr (NPART == 0) {
      v = ld4(&Asrc[(size_t)b * K + k0 + 4 * k4]);
    } else {
      v = ld4(&bias_in[k0 + 4 * k4]);
      #pragma unroll
      for (int p = 0; p < NPART; ++p) {
        float4 t = ld4(&Asrc[((size_t)p * 8 + b) * K + k0 + 4 * k4]);
        v.x += t.x; v.y += t.y; v.z += t.z; v.w += t.w;
      }
      if constexpr (RELU_IN) {
        v.x = fmaxf(v.x, 0.f); v.y = fmaxf(v.y, 0.f);
        v.z = fmaxf(v.z, 0.f); v.w = fmaxf(v.w, 0.f);
      }
    }
    st4(&A_lds[b][4 * k4], v);
    if constexpr (WRITE_STAGE) {
      if (cb == 0) st4(&stage_out[(size_t)b * K + k0 + 4 * k4], v);
    }
  }
  __syncthreads();

  // ---- main loop: 16 col-groups (float4) x 16 k-slices
  const int g  = tid & 15, ks = tid >> 4;
  const int c0 = cb * 64 + g * 4;
  float4 acc[8];
  #pragma unroll
  for (int b = 0; b < 8; ++b) acc[b] = make_float4(0.f, 0.f, 0.f, 0.f);

  const float* Wp = &W[(size_t)(k0 + ks * KT) * N + c0];
  #pragma unroll
  for (int i = 0; i < KT; i += 4) {
    const float4 w0 = ld4(Wp + (size_t)(i + 0) * N);
    const float4 w1 = ld4(Wp + (size_t)(i + 1) * N);
    const float4 w2 = ld4(Wp + (size_t)(i + 2) * N);
    const float4 w3 = ld4(Wp + (size_t)(i + 3) * N);
    const int kk = ks * KT + i;
    #pragma unroll
    for (int b = 0; b < 8; ++b) {
      const float4 a = ld4(&A_lds[b][kk]);   // broadcast within 16-lane group
      acc[b].x += a.x * w0.x + a.y * w1.x + a.z * w2.x + a.w * w3.x;
      acc[b].y += a.x * w0.y + a.y * w1.y + a.z * w2.y + a.w * w3.y;
      acc[b].z += a.x * w0.z + a.y * w1.z + a.z * w2.z + a.w * w3.z;
      acc[b].w += a.x * w0.w + a.y * w1.w + a.z * w2.w + a.w * w3.w;
    }
  }

  // ---- reduce the 16 k-slices through LDS
  __syncthreads();
  #pragma unroll
  for (int b = 0; b < 8; ++b) st4(&red[ks][b][g * 4], acc[b]);
  __syncthreads();

  for (int p = tid; p < 512; p += 256) {
    const int c = p & 63, b = p >> 6;
    float s = 0.f;
    #pragma unroll
    for (int j = 0; j < 16; ++j) s += red[j][b][c];
    Cparts[((size_t)kb * 8 + b) * N + cb * 64 + c] = s;
  }
}

// logits[8][5120] = sum of 4 partials + b3
__global__ __launch_bounds__(256)
void finalize_logits(const float* __restrict__ parts, const float* __restrict__ b3,
                     float* __restrict__ logits)
{
  const int i  = blockIdx.x * 256 + threadIdx.x;   // 10240 float4s, grid exact
  const int b  = i / 1280, k4 = i - b * 1280;
  float4 v = ld4(&b3[4 * k4]);
  #pragma unroll
  for (int p = 0; p < 4; ++p) {
    const float4 t = ld4(&parts[((size_t)p * 8 + b) * NOUT + 4 * k4]);
    v.x += t.x; v.y += t.y; v.z += t.z; v.w += t.w;
  }
  st4(&logits[(size_t)b * NOUT + 4 * k4], v);
}

// out[b][o] = max_k logits[b][k] * CM[o][k]
// 1 wave per block, 4 CM rows, FULL k-walk (rows read sequentially by one
// wave -> DRAM/L3 locality). No LDS, no barriers, no partials. Register
// double-buffer: chunk i+1's 12 independent 1KB wave-loads are issued
// before chunk i's compute. 1280 blocks = 5 blocks/CU.
__global__ __launch_bounds__(64)
void tropical4(const float* __restrict__ logits, const float* __restrict__ CM,
               float* __restrict__ out)
{
  const int l  = threadIdx.x;          // lane 0..63
  const int o0 = blockIdx.x * 4;       // 4 CM rows per wave

  const float* cmp = &CM[(size_t)o0 * NOUT + 4 * l];
  const float* lgp = &logits[4 * l];

  float4 cm[2][4], lv[2][8];
  #pragma unroll
  for (int r = 0; r < 4; ++r) cm[0][r] = ld4(cmp + (size_t)r * NOUT);
  #pragma unroll
  for (int b = 0; b < 8; ++b) lv[0][b] = ld4(lgp + (size_t)b * NOUT);

  float pmax[4][8];
  #pragma unroll
  for (int r = 0; r < 4; ++r)
    #pragma unroll
    for (int b = 0; b < 8; ++b) pmax[r][b] = -3.402823466e38f;

  #pragma unroll
  for (int i = 0; i < 20; ++i) {       // 20 chunks of 256 floats; full unroll
    const int cur = i & 1, nxt = cur ^ 1;
    if (i < 19) {
      const int off = 256 * (i + 1);   // next chunk: 64 lanes * float4
      #pragma unroll
      for (int r = 0; r < 4; ++r) cm[nxt][r] = ld4(cmp + (size_t)r * NOUT + off);
      #pragma unroll
      for (int b = 0; b < 8; ++b) lv[nxt][b] = ld4(lgp + (size_t)b * NOUT + off);
    }
    #pragma unroll
    for (int b = 0; b < 8; ++b) {
      const float4 L = lv[cur][b];
      #pragma unroll
      for (int r = 0; r < 4; ++r) {
        const float4 C = cm[cur][r];
        const float m0 = fmaxf(L.x * C.x, L.y * C.y);
        const float m1 = fmaxf(L.z * C.z, L.w * C.w);
        pmax[r][b] = fmaxf(pmax[r][b], fmaxf(m0, m1));
      }
    }
  }

  // cross-lane max reduce; lane 0 writes out[b][o]
  #pragma unroll
  for (int r = 0; r < 4; ++r) {
    #pragma unroll
    for (int b = 0; b < 8; ++b) {
      float v = pmax[r][b];
      for (int m = 32; m; m >>= 1) v = fmaxf(v, __shfl_xor(v, m));
      if (l == 0) out[(size_t)b * NOUT + o0 + r] = v;
    }
  }
}

extern "C" void kernel_launch(void* const* d_in, const int* in_sizes, int n_in,
                              void* d_out, int out_size, void* d_ws, size_t ws_size,
                              hipStream_t stream)
{
  const float* x  = (const float*)d_in[0];
  const float* W1 = (const float*)d_in[1];
  const float* b1 = (const float*)d_in[2];
  const float* W2 = (const float*)d_in[3];
  const float* b2 = (const float*)d_in[4];
  const float* W3 = (const float*)d_in[5];
  const float* b3 = (const float*)d_in[6];
  const float* CM = (const float*)d_in[7];

  float* out  = (float*)d_out;            // [8][5120]
  float* feat = out + B8 * NOUT;          // [8][1024]

  float* ws      = (float*)d_ws;
  float* parts1  = ws;                      // [ 8][8][2048] = 131072 f
  float* parts2  = parts1 + 8  * 8 * NH1;   // [16][8][1024] = 131072 f
  float* parts3  = parts2 + 16 * 8 * NH2;   // [ 4][8][5120] = 163840 f
  float* logits  = parts3 + 4  * 8 * NOUT;  // [8][5120]     =  40960 f

  // h1 partials: x[8,1024] @ W1[1024,2048], K split 8 -> 256 blocks
  gemm8<DIN, NH1, 8, 0, false, false><<<256, 256, 0, stream>>>(x, nullptr, W1, parts1, nullptr);
  // h2 partials: relu(sum parts1 + b1) @ W2[2048,1024], K split 16 -> 256 blocks
  gemm8<NH1, NH2, 16, 8, true, false><<<256, 256, 0, stream>>>(parts1, b1, W2, parts2, nullptr);
  // logits partials: relu(sum parts2 + b2) @ W3[1024,5120], K split 4 -> 320 blocks
  // (staged A == features; written by cb==0 blocks)
  gemm8<NH2, NOUT, 4, 16, true, true><<<320, 256, 0, stream>>>(parts2, b2, W3, parts3, feat);
  // logits = sum parts3 + b3
  finalize_logits<<<40, 256, 0, stream>>>(parts3, b3, logits);
  // tropical max-product: 1280 single-wave blocks, 4 rows each, full k-walk
  tropical4<<<1280, 64, 0, stream>>>(logits, CM, out);
}

// Round 5
// 52.402 us; speedup vs baseline: 6.2056x; 6.2056x over previous
//
#include <hip/hip_runtime.h>
#include <cstdint>

#define B8   8
#define DIN  1024
#define NH1  2048
#define NH2  1024
#define NOUT 5120

__device__ __forceinline__ float4 ld4(const float* p) {
  return *reinterpret_cast<const float4*>(p);
}
__device__ __forceinline__ void st4(float* p, float4 v) {
  *reinterpret_cast<float4*>(p) = v;
}

// C_parts[kb][8][N] = A[8, k0:k0+KC] @ W[k0:k0+KC, :]   (partial over K-chunk)
// A source: raw input (NPART==0) or sum of NPART partials + bias (+ReLU).
// The staged (finalized) A chunk is optionally written out (features).
template<int K, int N, int KSPLIT, int NPART, bool RELU_IN, bool WRITE_STAGE>
__global__ __launch_bounds__(256)
void gemm8(const float* __restrict__ Asrc, const float* __restrict__ bias_in,
           const float* __restrict__ W, float* __restrict__ Cparts,
           float* __restrict__ stage_out)
{
  constexpr int KC    = K / KSPLIT;   // k-chunk per block
  constexpr int KC4   = KC / 4;
  constexpr int NCOLB = N / 64;       // 64 output cols per block
  constexpr int KT    = KC / 16;      // k elements per thread

  __shared__ float A_lds[8][KC];      // <= 8 KB
  __shared__ float red[16][8][64];    // 32 KB

  const int tid = threadIdx.x;
  const int kb  = blockIdx.x / NCOLB;
  const int cb  = blockIdx.x % NCOLB;
  const int k0  = kb * KC;

  // ---- stage A chunk into LDS (finalize previous stage: sum partials + bias + relu)
  for (int e = tid; e < 8 * KC4; e += 256) {
    const int b = e / KC4, k4 = e - b * KC4;
    float4 v;
    if constexpr (NPART == 0) {
      v = ld4(&Asrc[(size_t)b * K + k0 + 4 * k4]);
    } else {
      v = ld4(&bias_in[k0 + 4 * k4]);
      #pragma unroll
      for (int p = 0; p < NPART; ++p) {
        float4 t = ld4(&Asrc[((size_t)p * 8 + b) * K + k0 + 4 * k4]);
        v.x += t.x; v.y += t.y; v.z += t.z; v.w += t.w;
      }
      if constexpr (RELU_IN) {
        v.x = fmaxf(v.x, 0.f); v.y = fmaxf(v.y, 0.f);
        v.z = fmaxf(v.z, 0.f); v.w = fmaxf(v.w, 0.f);
      }
    }
    st4(&A_lds[b][4 * k4], v);
    if constexpr (WRITE_STAGE) {
      if (cb == 0) st4(&stage_out[(size_t)b * K + k0 + 4 * k4], v);
    }
  }
  __syncthreads();

  // ---- main loop: 16 col-groups (float4) x 16 k-slices
  const int g  = tid & 15, ks = tid >> 4;
  const int c0 = cb * 64 + g * 4;
  float4 acc[8];
  #pragma unroll
  for (int b = 0; b < 8; ++b) acc[b] = make_float4(0.f, 0.f, 0.f, 0.f);

  const float* Wp = &W[(size_t)(k0 + ks * KT) * N + c0];
  #pragma unroll
  for (int i = 0; i < KT; i += 4) {
    const float4 w0 = ld4(Wp + (size_t)(i + 0) * N);
    const float4 w1 = ld4(Wp + (size_t)(i + 1) * N);
    const float4 w2 = ld4(Wp + (size_t)(i + 2) * N);
    const float4 w3 = ld4(Wp + (size_t)(i + 3) * N);
    const int kk = ks * KT + i;
    #pragma unroll
    for (int b = 0; b < 8; ++b) {
      const float4 a = ld4(&A_lds[b][kk]);   // broadcast within 16-lane group
      acc[b].x += a.x * w0.x + a.y * w1.x + a.z * w2.x + a.w * w3.x;
      acc[b].y += a.x * w0.y + a.y * w1.y + a.z * w2.y + a.w * w3.y;
      acc[b].z += a.x * w0.z + a.y * w1.z + a.z * w2.z + a.w * w3.z;
      acc[b].w += a.x * w0.w + a.y * w1.w + a.z * w2.w + a.w * w3.w;
    }
  }

  // ---- reduce the 16 k-slices through LDS
  __syncthreads();
  #pragma unroll
  for (int b = 0; b < 8; ++b) st4(&red[ks][b][g * 4], acc[b]);
  __syncthreads();

  for (int p = tid; p < 512; p += 256) {
    const int c = p & 63, b = p >> 6;
    float s = 0.f;
    #pragma unroll
    for (int j = 0; j < 16; ++j) s += red[j][b][c];
    Cparts[((size_t)kb * 8 + b) * N + cb * 64 + c] = s;
  }
}

// logits[8][5120] = sum of 4 partials + b3
__global__ __launch_bounds__(256)
void finalize_logits(const float* __restrict__ parts, const float* __restrict__ b3,
                     float* __restrict__ logits)
{
  const int i  = blockIdx.x * 256 + threadIdx.x;   // 10240 float4s, grid exact
  const int b  = i / 1280, k4 = i - b * 1280;
  float4 v = ld4(&b3[4 * k4]);
  #pragma unroll
  for (int p = 0; p < 4; ++p) {
    const float4 t = ld4(&parts[((size_t)p * 8 + b) * NOUT + 4 * k4]);
    v.x += t.x; v.y += t.y; v.z += t.z; v.w += t.w;
  }
  st4(&logits[(size_t)b * NOUT + 4 * k4], v);
}

// out[b][o] = max_k logits[b][k] * CM[o][k]
// R0's monolithic structure at 2x block count and hoisted cm loads:
// 640 blocks x 256 thr (4 waves); block owns 8 CM rows, 2 per wave.
// Full k-walk in 5 LDS-staged chunks of [8][1024] (32 KB -> 5 blocks/CU
// LDS-cap, 2.5 co-resident here = 10 waves/CU). Per chunk each wave hoists
// its 8 cm float4 loads (independent, 8 KB in flight) before the
// LDS-read/VALU phase; each LDS read is reused across 2 rows.
__global__ __launch_bounds__(256)
void tropical8(const float* __restrict__ logits, const float* __restrict__ CM,
               float* __restrict__ out)
{
  __shared__ float L[8][1024];   // 32 KB logits chunk

  const int tid = threadIdx.x;
  const int w   = tid >> 6;      // wave 0..3
  const int l   = tid & 63;      // lane
  const int o0  = blockIdx.x * 8 + w * 2;   // this wave's 2 CM rows

  float pmax[2][8];
  #pragma unroll
  for (int r = 0; r < 2; ++r)
    #pragma unroll
    for (int b = 0; b < 8; ++b) pmax[r][b] = -3.402823466e38f;

  for (int ck = 0; ck < NOUT; ck += 1024) {
    // stage logits chunk (2048 float4s over 256 threads)
    for (int e = tid; e < 2048; e += 256) {
      const int b = e >> 8, k4 = e & 255;
      st4(&L[b][4 * k4], ld4(&logits[(size_t)b * NOUT + ck + 4 * k4]));
    }

    // hoist this wave's 8 cm loads for the chunk (2 rows x 4 sub-chunks)
    float4 cm[2][4];
    #pragma unroll
    for (int r = 0; r < 2; ++r) {
      const float* cmrow = &CM[(size_t)(o0 + r) * NOUT + ck + 4 * l];
      #pragma unroll
      for (int i = 0; i < 4; ++i) cm[r][i] = ld4(cmrow + 256 * i);
    }

    __syncthreads();

    #pragma unroll
    for (int i = 0; i < 4; ++i) {
      const int kk = 4 * l + 256 * i;
      #pragma unroll
      for (int b = 0; b < 8; ++b) {
        const float4 lv = ld4(&L[b][kk]);
        #pragma unroll
        for (int r = 0; r < 2; ++r) {
          const float4 C = cm[r][i];
          const float m0 = fmaxf(lv.x * C.x, lv.y * C.y);
          const float m1 = fmaxf(lv.z * C.z, lv.w * C.w);
          pmax[r][b] = fmaxf(pmax[r][b], fmaxf(m0, m1));
        }
      }
    }
    __syncthreads();
  }

  // cross-lane max reduce; lane 0 writes
  #pragma unroll
  for (int r = 0; r < 2; ++r) {
    #pragma unroll
    for (int b = 0; b < 8; ++b) {
      float v = pmax[r][b];
      for (int m = 32; m; m >>= 1) v = fmaxf(v, __shfl_xor(v, m));
      if (l == 0) out[(size_t)b * NOUT + o0 + r] = v;
    }
  }
}

extern "C" void kernel_launch(void* const* d_in, const int* in_sizes, int n_in,
                              void* d_out, int out_size, void* d_ws, size_t ws_size,
                              hipStream_t stream)
{
  const float* x  = (const float*)d_in[0];
  const float* W1 = (const float*)d_in[1];
  const float* b1 = (const float*)d_in[2];
  const float* W2 = (const float*)d_in[3];
  const float* b2 = (const float*)d_in[4];
  const float* W3 = (const float*)d_in[5];
  const float* b3 = (const float*)d_in[6];
  const float* CM = (const float*)d_in[7];

  float* out  = (float*)d_out;            // [8][5120]
  float* feat = out + B8 * NOUT;          // [8][1024]

  float* ws      = (float*)d_ws;
  float* parts1  = ws;                      // [ 8][8][2048] = 131072 f
  float* parts2  = parts1 + 8  * 8 * NH1;   // [16][8][1024] = 131072 f
  float* parts3  = parts2 + 16 * 8 * NH2;   // [ 4][8][5120] = 163840 f
  float* logits  = parts3 + 4  * 8 * NOUT;  // [8][5120]     =  40960 f

  // h1 partials: x[8,1024] @ W1[1024,2048], K split 8 -> 256 blocks
  gemm8<DIN, NH1, 8, 0, false, false><<<256, 256, 0, stream>>>(x, nullptr, W1, parts1, nullptr);
  // h2 partials: relu(sum parts1 + b1) @ W2[2048,1024], K split 16 -> 256 blocks
  gemm8<NH1, NH2, 16, 8, true, false><<<256, 256, 0, stream>>>(parts1, b1, W2, parts2, nullptr);
  // logits partials: relu(sum parts2 + b2) @ W3[1024,5120], K split 4 -> 320 blocks
  // (staged A == features; written by cb==0 blocks)
  gemm8<NH2, NOUT, 4, 16, true, true><<<320, 256, 0, stream>>>(parts2, b2, W3, parts3, feat);
  // logits = sum parts3 + b3
  finalize_logits<<<40, 256, 0, stream>>>(parts3, b3, logits);
  // tropical max-product: 640 blocks x 8 rows, full k-walk, LDS-staged logits
  tropical8<<<640, 256, 0, stream>>>(logits, CM, out);
}